// Round 12
// baseline (111.836 us; speedup 1.0000x reference)
//
#include <hip/hip_runtime.h>
#include <stdint.h>

#define DROI   12544
#define BIMG   16
#define NDET   128
#define NHID   128

typedef __bf16 bf16x8 __attribute__((ext_vector_type(8)));
typedef float  f32x4  __attribute__((ext_vector_type(4)));

// ---------------- helpers ----------------
__device__ __forceinline__ unsigned pk2(float a, float b){
  unsigned ua = __float_as_uint(a), ub = __float_as_uint(b);
  ua = (ua + 0x7fffu + ((ua >> 16) & 1u)) >> 16;
  ub = (ub + 0x7fffu + ((ub >> 16) & 1u)) >> 16;
  return ua | (ub << 16);
}
__device__ __forceinline__ unsigned short bf1(float a){
  unsigned ua = __float_as_uint(a);
  return (unsigned short)((ua + 0x7fffu + ((ua >> 16) & 1u)) >> 16);
}
__device__ __forceinline__ f32x4 mfma16(bf16x8 a, bf16x8 b, f32x4 c){
  return __builtin_amdgcn_mfma_f32_16x16x32_bf16(a, b, c, 0, 0, 0);
}
__device__ __forceinline__ void gl_lds16(const void* g, void* l){
  __builtin_amdgcn_global_load_lds(
      (const __attribute__((address_space(1))) unsigned int*)g,
      (__attribute__((address_space(3))) unsigned int*)l, 16, 0, 0);
}
// 128-byte-row tile (128 rows x 64 bf16), XOR-swizzled
__device__ __forceinline__ bf16x8 ldfrag128(const short* base, int row, int bo){
  const char* p = (const char*)base + row * 128 + (bo ^ ((row & 7) << 4));
  return *(const bf16x8*)p;
}
// 256-byte-row tile (128 rows x 128 bf16), XOR-swizzled
__device__ __forceinline__ bf16x8 ldfrag256(const short* base, int row, int bo){
  const char* p = (const char*)base + row * 256 + (bo ^ ((row & 7) << 4));
  return *(const bf16x8*)p;
}

// ---------------- K0: W1[:12544][:] -> Wt bf16 [128][12544] ----------------
__global__ __launch_bounds__(256) void k0_wt(const float* __restrict__ W1,
                                             unsigned short* __restrict__ Wt){
  __shared__ float tile[64][133];
  const int t  = threadIdx.x;
  const int k0 = blockIdx.x * 64;
  const int r0 = t >> 5;
  const int c4 = (t & 31) * 4;
#pragma unroll
  for (int i = 0; i < 8; ++i){
    int r = r0 + i * 8;
    float4 v = *(const float4*)(W1 + (long)(k0 + r) * NHID + c4);
    tile[r][c4+0] = v.x; tile[r][c4+1] = v.y; tile[r][c4+2] = v.z; tile[r][c4+3] = v.w;
  }
  __syncthreads();
  const int h  = t >> 1;
  const int kc = (t & 1) * 32;
  unsigned* dst = (unsigned*)(Wt + (long)h * DROI + k0 + kc);
#pragma unroll
  for (int kk = 0; kk < 32; kk += 2)
    dst[kk >> 1] = pk2(tile[kc + kk][h], tile[kc + kk + 1][h]);
}

// ---------------- K1: fused Gram + fv@W1, producer-consumer ----------------
// 640 threads: waves 0-7 = consumers (r7 compute mapping, issue NO VMEM in
// the loop); waves 8-9 = producers (all staging: Wt via global_load_lds,
// fv load->convert->ds_write). Plain __syncthreads only — its vmcnt/lgkm
// drain is paid by producer waves and hidden under consumer MFMAs.
template<int SK>
__global__ __launch_bounds__(640, 2) void k1_main(const float* __restrict__ fv,
    const unsigned short* __restrict__ Wt, unsigned* __restrict__ part){
  constexpr int KC = DROI / SK;     // 896 at SK=14
  constexpr int NT = KC / 64;       // 14
  static_assert(NT >= 2, "need >=2 tiles");
  __shared__ __align__(16) short lsA[2][8192];   // fv tile bf16 (16KB each)
  __shared__ __align__(16) short lsB[2][8192];   // Wt tile bf16 (16KB each)
  const int tid  = threadIdx.x;
  const int wave = tid >> 6, lane = tid & 63;

  // XCD-aware swizzle (nwg = SK*16, divisible by 8)
  const int nwg  = SK * BIMG;
  const int cpx  = nwg >> 3;
  const int orig = blockIdx.x;
  const int wg   = (orig & 7) * cpx + (orig >> 3);
  const int s = wg >> 4;
  const int b = wg & 15;
  const int kbase = s * KC;

  const int hh  = lane >> 3;
  const int seg = (lane & 7) ^ hh;

  // ---- producer state (valid for waves 8-9 only) ----
  const int pt   = tid - 512;          // 0..127
  const int prow = pt >> 4;            // row offset 0..7 within 8-row group
  const int pcol = (pt & 15) * 4;      // f32 col 0..60
  const int psw  = (prow & 7) << 4;    // row&7 == prow for all groups
  const float* fvp = fv + (long)(b * NDET + prow) * DROI + kbase + pcol;
  const int pw = wave - 8;             // 0..1

  auto produce = [&](int t, int bufi){
    // Wt tile (16KB): 8 gl_lds calls per producer wave, calls 0..15 total
#pragma unroll
    for (int j = 0; j < 8; ++j){
      int call = pw * 8 + j;
      int h = call * 8 + hh;
      const char* g = (const char*)Wt + (long)h * (DROI * 2)
                    + (long)(kbase + t * 64) * 2 + seg * 16;
      gl_lds16(g, (char*)lsB[bufi] + call * 1024);
    }
    // fv tile (32KB f32 -> 16KB bf16): 16 coalesced float4 loads/lane,
    // 4 batches of 4 to bound live registers
    char* basep = (char*)lsA[bufi];
    const float* fp = fvp + t * 64;
#pragma unroll
    for (int batch = 0; batch < 4; ++batch){
      float4 v[4];
#pragma unroll
      for (int i = 0; i < 4; ++i)
        v[i] = *(const float4*)(fp + (long)((batch * 4 + i) * 8) * DROI);
#pragma unroll
      for (int i = 0; i < 4; ++i){
        int row = (batch * 4 + i) * 8 + prow;
        uint2 w; w.x = pk2(v[i].x, v[i].y); w.y = pk2(v[i].z, v[i].w);
        *(uint2*)(basep + row * 128 + ((pcol * 2) ^ psw)) = w;
      }
    }
  };

  // ---- consumer state ----
  const int outw = wave >> 2;          // 0 = Gram, 1 = XW1 (waves 0-7)
  const int mq   = wave & 3;
  const int lq   = lane & 15;
  f32x4 acc[2][8];
  {
    f32x4 z = {0.f, 0.f, 0.f, 0.f};
#pragma unroll
    for (int m = 0; m < 2; ++m)
#pragma unroll
      for (int c = 0; c < 8; ++c) acc[m][c] = z;
  }

  // ---- prologue: producers fill tile 0 ----
  if (wave >= 8) produce(0, 0);
  __syncthreads();

  for (int t = 0; t < NT; ++t){
    if (wave < 8){
      const short* A  = lsA[t & 1];
      const short* Bs = outw ? (const short*)lsB[t & 1] : A;
#pragma unroll
      for (int kk = 0; kk < 2; ++kk){
        const int bo = kk * 64 + (lane >> 4) * 16;
        bf16x8 a0 = ldfrag128(A, mq * 32 + lq, bo);
        bf16x8 a1 = ldfrag128(A, mq * 32 + 16 + lq, bo);
#pragma unroll
        for (int cb = 0; cb < 8; ++cb){
          bf16x8 bb = ldfrag128(Bs, cb * 16 + lq, bo);
          acc[0][cb] = mfma16(a0, bb, acc[0][cb]);
          acc[1][cb] = mfma16(a1, bb, acc[1][cb]);
        }
      }
    } else if (t + 1 < NT){
      produce(t + 1, (t + 1) & 1);
    }
    __syncthreads();
  }

  // ---- bf16 packed, fully-coalesced partial store (consumers only) ----
  if (wave < 8){
    const int slot = mq * 64 + lane;
    uint4* dst4 = (uint4*)(part + (((long)s * 32 + b * 2 + outw) * 8192));
#pragma unroll
    for (int g = 0; g < 8; ++g){
      const int m = g >> 2, cb0 = (g & 3) * 2;
      uint4 w;
      w.x = pk2(acc[m][cb0][0],     acc[m][cb0][1]);
      w.y = pk2(acc[m][cb0][2],     acc[m][cb0][3]);
      w.z = pk2(acc[m][cb0 + 1][0], acc[m][cb0 + 1][1]);
      w.w = pk2(acc[m][cb0 + 1][2], acc[m][cb0 + 1][3]);
      dst4[g * 256 + slot] = w;
    }
  }
}

// ---------------- KR: split-K reduce (r7 decode), coalesced both sides -----
template<int SK>
__global__ __launch_bounds__(256) void k_reduce(const unsigned* __restrict__ part,
                                                float* __restrict__ fin){
  __shared__ float tile[16][33];
  const int tid = threadIdx.x;
  const int B   = blockIdx.x;            // 0..1023
  const int bo2 = B >> 5;                // b*2 + outw
  const int q   = (B & 31) * 256 + tid;  // within-part uint index
  float lo = 0.f, hi = 0.f;
  const unsigned* p = part + (long)bo2 * 8192 + q;
#pragma unroll
  for (int s = 0; s < SK; ++s){
    unsigned v = p[(long)s * 262144];
    lo += __uint_as_float(v << 16);
    hi += __uint_as_float(v & 0xffff0000u);
  }
  const int g    = q >> 10;
  const int slot = (q & 1023) >> 2;
  const int w    = q & 3;
  const int m  = g >> 2;
  const int cb1 = w >> 1;
  const int ip = w & 1;
  const int mq = slot >> 6, lane = slot & 63;
  const int r   = ((lane >> 4) << 2) + (ip << 1);
  const int col = (cb1 << 4) + (lane & 15);
  tile[r][col]     = lo;
  tile[r + 1][col] = hi;
  __syncthreads();
  const int Rbase = mq * 32 + m * 16;
  const int Cbase = (g & 3) * 32;
  float* f = fin + (long)bo2 * 16384;
  if ((bo2 & 1) == 0){
#pragma unroll
    for (int k = 0; k < 2; ++k){
      int idx = k * 256 + tid;
      int rr = idx >> 5, cc = idx & 31;
      f[(Rbase + rr) * 128 + Cbase + cc] = tile[rr][cc];
    }
  } else {
#pragma unroll
    for (int k = 0; k < 2; ++k){
      int idx = k * 256 + tid;
      int cc = idx >> 4, rr = idx & 15;
      f[(Cbase + cc) * 128 + Rbase + rr] = tile[rr][cc];
    }
  }
}

// ---------------- K2: fused adjacency + 3 GEMMs + pool + logits, 512 thr ---
__global__ __launch_bounds__(512, 1) void k2f(const float* __restrict__ fin,
    const float* __restrict__ ctr, const float* __restrict__ W1,
    const float* __restrict__ b1, const float* __restrict__ W2,
    const float* __restrict__ b2, const float* __restrict__ Wc,
    const float* __restrict__ bc, float* __restrict__ out){
  __shared__ __align__(16) short Ah[16384];   // normalized adjacency (persistent)
  __shared__ __align__(16) short Bu[16384];   // Yt -> H1 -> Tt
  __shared__ __align__(16) short Cu[16384];   // W2t -> pool scratch
  __shared__ float sm2[256];
  __shared__ float sctr[256];
  const int b   = blockIdx.x;
  const int tid = threadIdx.x;
  const float* G  = fin + (long)b * 32768;
  const float* Yt = G + 16384;                // stored TRANSPOSED: Yt[c][k]

  if (tid < 256) sctr[tid] = ctr[b * 256 + tid];
  if (tid < 128){
    float g = G[tid * 129];
    sm2[tid] = 1.0f / fmaxf(sqrtf(g), 1e-12f);
  }
  __syncthreads();

  // adjacency: thread (i, j-quarter of 32)
  const int   i   = tid >> 2;
  const int   jq  = (tid & 3) * 32;
  const float invni = sm2[i];
  const float cxi = sctr[2 * i], cyi = sctr[2 * i + 1];
  unsigned m0 = 0;
  int degloc = 0;
  for (int j4 = 0; j4 < 32; j4 += 4){
    float4 g4 = *(const float4*)(G + i * 128 + jq + j4);
    float gg[4] = {g4.x, g4.y, g4.z, g4.w};
#pragma unroll
    for (int u = 0; u < 4; ++u){
      int j = jq + j4 + u;
      float cs = gg[u] * invni * sm2[j];
      float dx = cxi - sctr[2 * j];
      float dy = cyi - sctr[2 * j + 1];
      float d2 = dx * dx + dy * dy;
      if (d2 < 2500.0f || cs > 0.8f){
        m0 |= (1u << (j4 + u));
        ++degloc;
      }
    }
  }
  if (i >= jq && i < jq + 32) ++degloc;       // self loop
  degloc += __shfl_xor(degloc, 1);
  degloc += __shfl_xor(degloc, 2);
  if ((tid & 3) == 0) sm2[128 + i] = rsqrtf((float)degloc);
  __syncthreads();

  {
    const float dinvi = sm2[128 + i];
    char* AhB = (char*)Ah;
#pragma unroll
    for (int jp = 0; jp < 32; jp += 2){
      int j0 = jq + jp, j1 = j0 + 1;
      float a0 = ((m0 >> jp)       & 1u) ? 1.f : 0.f;
      float a1 = ((m0 >> (jp + 1)) & 1u) ? 1.f : 0.f;
      if (i == j0) a0 += 1.f;
      if (i == j1) a1 += 1.f;
      float v0 = dinvi * a0 * sm2[128 + j0];
      float v1 = dinvi * a1 * sm2[128 + j1];
      int bo = j0 * 2;
      *(unsigned*)(AhB + i * 256 + (bo ^ ((i & 7) << 4))) = pk2(v0, v1);
    }
  }

  // stage W2t[c][k] into Cu (4 threads per col, 32 k each)
  {
    const int c  = tid & 127;
    const int kq = (tid >> 7) * 32;
    char* WB = (char*)Cu;
#pragma unroll
    for (int k8 = kq; k8 < kq + 32; k8 += 8){
      float f[8];
#pragma unroll
      for (int u = 0; u < 8; ++u) f[u] = W2[(k8 + u) * 128 + c];
      uint4 w;
      w.x = pk2(f[0], f[1]); w.y = pk2(f[2], f[3]);
      w.z = pk2(f[4], f[5]); w.w = pk2(f[6], f[7]);
      int bo = k8 * 2;
      *(uint4*)(WB + c * 256 + (bo ^ ((c & 7) << 4))) = w;
    }
  }
  // stage Yt tile from transposed fin + ctr tail (4 threads per row, 32 k)
  {
    const int cr = tid >> 2;
    const int kq = (tid & 3) * 32;
    const float w1a = W1[(long)12544 * NHID + cr];
    const float w1b = W1[(long)12545 * NHID + cr];
    const float* Yr = Yt + cr * 128 + kq;
    char* YtB = (char*)Bu;
#pragma unroll
    for (int k8 = 0; k8 < 32; k8 += 8){
      float4 va = *(const float4*)(Yr + k8);
      float4 vb = *(const float4*)(Yr + k8 + 4);
      float f[8] = {va.x, va.y, va.z, va.w, vb.x, vb.y, vb.z, vb.w};
#pragma unroll
      for (int u = 0; u < 8; ++u){
        int k = kq + k8 + u;
        f[u] += sctr[2 * k] * w1a + sctr[2 * k + 1] * w1b;
      }
      uint4 w;
      w.x = pk2(f[0], f[1]); w.y = pk2(f[2], f[3]);
      w.z = pk2(f[4], f[5]); w.w = pk2(f[6], f[7]);
      int bo = (kq + k8) * 2;
      *(uint4*)(YtB + cr * 256 + (bo ^ ((cr & 7) << 4))) = w;
    }
  }
  __syncthreads();

  const int wave = tid >> 6, lane = tid & 63;
  const int lq = lane & 15;
  f32x4 acc[8];
  f32x4 z4 = {0.f, 0.f, 0.f, 0.f};

  // GEMM1: H1 = relu(Ah @ Yt + b1) — wave owns 16 rows
#pragma unroll
  for (int cc = 0; cc < 8; ++cc) acc[cc] = z4;
#pragma unroll
  for (int ks = 0; ks < 4; ++ks){
    const int bo = ks * 64 + (lane >> 4) * 16;
    bf16x8 a0 = ldfrag256(Ah, wave * 16 + lq, bo);
#pragma unroll
    for (int cb = 0; cb < 8; ++cb){
      bf16x8 bb = ldfrag256(Bu, cb * 16 + lq, bo);
      acc[cb] = mfma16(a0, bb, acc[cb]);
    }
  }
  __syncthreads();
  {
    char* BuB = (char*)Bu;
    const int R0 = wave * 16 + (lane >> 4) * 4;
#pragma unroll
    for (int cb = 0; cb < 8; ++cb){
      const int C = cb * 16 + lq;
      const float bb1 = b1[C];
#pragma unroll
      for (int u = 0; u < 4; ++u){
        float v = fmaxf(acc[cb][u] + bb1, 0.f);
        int row = R0 + u;
        *(unsigned short*)(BuB + row * 256 + ((C * 2) ^ ((row & 7) << 4))) = bf1(v);
      }
    }
  }
  __syncthreads();

  // GEMM2: T = H1 @ W2t
#pragma unroll
  for (int cc = 0; cc < 8; ++cc) acc[cc] = z4;
#pragma unroll
  for (int ks = 0; ks < 4; ++ks){
    const int bo = ks * 64 + (lane >> 4) * 16;
    bf16x8 a0 = ldfrag256(Bu, wave * 16 + lq, bo);
#pragma unroll
    for (int cb = 0; cb < 8; ++cb){
      bf16x8 bb = ldfrag256(Cu, cb * 16 + lq, bo);
      acc[cb] = mfma16(a0, bb, acc[cb]);
    }
  }
  __syncthreads();
  {
    char* BuB = (char*)Bu;
    const int R0 = wave * 16 + (lane >> 4) * 4;
#pragma unroll
    for (int cb = 0; cb < 8; ++cb){
      const int C = cb * 16 + lq;
#pragma unroll
      for (int u = 0; u < 4; u += 2){
        int k = R0 + u;   // even
        unsigned w = pk2(acc[cb][u], acc[cb][u + 1]);
        *(unsigned*)(BuB + C * 256 + ((k * 2) ^ ((C & 7) << 4))) = w;
      }
    }
  }
  __syncthreads();

  // GEMM3: C2 = Ah @ Tt; relu(+b2); mean pool; logits
#pragma unroll
  for (int cc = 0; cc < 8; ++cc) acc[cc] = z4;
#pragma unroll
  for (int ks = 0; ks < 4; ++ks){
    const int bo = ks * 64 + (lane >> 4) * 16;
    bf16x8 a0 = ldfrag256(Ah, wave * 16 + lq, bo);
#pragma unroll
    for (int cb = 0; cb < 8; ++cb){
      bf16x8 bb = ldfrag256(Bu, cb * 16 + lq, bo);
      acc[cb] = mfma16(a0, bb, acc[cb]);
    }
  }
  float colp[8];
#pragma unroll
  for (int cb = 0; cb < 8; ++cb){
    const float bb2 = b2[cb * 16 + lq];
    float sum = 0.f;
#pragma unroll
    for (int u = 0; u < 4; ++u)
      sum += fmaxf(acc[cb][u] + bb2, 0.f);
    colp[cb] = sum;
  }
#pragma unroll
  for (int cb = 0; cb < 8; ++cb){
    float v = colp[cb];
    v += __shfl_xor(v, 16);
    v += __shfl_xor(v, 32);
    colp[cb] = v;
  }
  float* hgp = (float*)Cu;            // [8][128] partial col sums (Cu dead after GEMM2)
  if ((lane >> 4) == 0){
#pragma unroll
    for (int cb = 0; cb < 8; ++cb)
      hgp[wave * 128 + cb * 16 + lane] = colp[cb];
  }
  __syncthreads();
  float* hg = hgp + 1024;
  if (tid < 128){
    float s = 0.f;
#pragma unroll
    for (int w = 0; w < 8; ++w) s += hgp[w * 128 + tid];
    hg[tid] = s * (1.0f / 128.0f);
  }
  __syncthreads();
  if (tid < 22){
    float a2 = bc[tid];
    for (int h = 0; h < 128; ++h) a2 += hg[h] * Wc[h * 22 + tid];
    out[b * 22 + tid] = a2;
  }
}

// ---------------- launch ----------------
extern "C" void kernel_launch(void* const* d_in, const int* in_sizes, int n_in,
                              void* d_out, int out_size, void* d_ws, size_t ws_size,
                              hipStream_t stream){
  (void)in_sizes; (void)n_in; (void)out_size; (void)ws_size;
  const float* fv  = (const float*)d_in[0];
  const float* ctr = (const float*)d_in[1];
  const float* W1  = (const float*)d_in[2];
  const float* b1  = (const float*)d_in[3];
  const float* W2  = (const float*)d_in[4];
  const float* b2  = (const float*)d_in[5];
  const float* Wc  = (const float*)d_in[6];
  const float* bc  = (const float*)d_in[7];
  char* ws = (char*)d_ws;
  float* out = (float*)d_out;

  const unsigned long SZ_WT = (unsigned long)NHID * DROI * 2;   // 3,211,264

  unsigned short* Wt   = (unsigned short*)(ws);
  unsigned*       part = (unsigned*)(ws + SZ_WT);
  float*          fin  = (float*)(ws + SZ_WT + 14UL * 1048576UL);

  k0_wt<<<dim3(DROI / 64), dim3(256), 0, stream>>>(W1, Wt);
  k1_main<14><<<dim3(14 * BIMG), dim3(640), 0, stream>>>(fv, Wt, part);
  k_reduce<14><<<dim3(1024), dim3(256), 0, stream>>>(part, fin);
  k2f<<<dim3(BIMG), dim3(512), 0, stream>>>(fin, ctr, W1, b1, W2, b2, Wc, bc, out);
}

// Round 13
// 58.927 us; speedup vs baseline: 1.8979x; 1.8979x over previous
//
#include <hip/hip_runtime.h>
#include <stdint.h>

#define DROI   12544
#define BIMG   16
#define NDET   128
#define NHID   128

typedef __bf16 bf16x8 __attribute__((ext_vector_type(8)));
typedef float  f32x4  __attribute__((ext_vector_type(4)));

// ---------------- helpers ----------------
__device__ __forceinline__ unsigned pk2(float a, float b){
  unsigned ua = __float_as_uint(a), ub = __float_as_uint(b);
  ua = (ua + 0x7fffu + ((ua >> 16) & 1u)) >> 16;
  ub = (ub + 0x7fffu + ((ub >> 16) & 1u)) >> 16;
  return ua | (ub << 16);
}
__device__ __forceinline__ unsigned short bf1(float a){
  unsigned ua = __float_as_uint(a);
  return (unsigned short)((ua + 0x7fffu + ((ua >> 16) & 1u)) >> 16);
}
__device__ __forceinline__ f32x4 mfma16(bf16x8 a, bf16x8 b, f32x4 c){
  return __builtin_amdgcn_mfma_f32_16x16x32_bf16(a, b, c, 0, 0, 0);
}
__device__ __forceinline__ void gl_lds16(const void* g, void* l){
  __builtin_amdgcn_global_load_lds(
      (const __attribute__((address_space(1))) unsigned int*)g,
      (__attribute__((address_space(3))) unsigned int*)l, 16, 0, 0);
}
// 128-byte-row tile (128 rows x 64 bf16), XOR-swizzled
__device__ __forceinline__ bf16x8 ldfrag128(const short* base, int row, int bo){
  const char* p = (const char*)base + row * 128 + (bo ^ ((row & 7) << 4));
  return *(const bf16x8*)p;
}
// 256-byte-row tile (128 rows x 128 bf16), XOR-swizzled
__device__ __forceinline__ bf16x8 ldfrag256(const short* base, int row, int bo){
  const char* p = (const char*)base + row * 256 + (bo ^ ((row & 7) << 4));
  return *(const bf16x8*)p;
}

// ---------------- K0: W1[:12544][:] -> Wt bf16 [128][12544] ----------------
__global__ __launch_bounds__(256) void k0_wt(const float* __restrict__ W1,
                                             unsigned short* __restrict__ Wt){
  __shared__ float tile[64][133];
  const int t  = threadIdx.x;
  const int k0 = blockIdx.x * 64;
  const int r0 = t >> 5;
  const int c4 = (t & 31) * 4;
#pragma unroll
  for (int i = 0; i < 8; ++i){
    int r = r0 + i * 8;
    float4 v = *(const float4*)(W1 + (long)(k0 + r) * NHID + c4);
    tile[r][c4+0] = v.x; tile[r][c4+1] = v.y; tile[r][c4+2] = v.z; tile[r][c4+3] = v.w;
  }
  __syncthreads();
  const int h  = t >> 1;
  const int kc = (t & 1) * 32;
  unsigned* dst = (unsigned*)(Wt + (long)h * DROI + k0 + kc);
#pragma unroll
  for (int kk = 0; kk < 32; kk += 2)
    dst[kk >> 1] = pk2(tile[kc + kk][h], tile[kc + kk + 1][h]);
}

// ---------------- K1: fused Gram + fv@W1, depth-1F/depth-2G pipeline -------
template<int SK>
__global__ __launch_bounds__(512, 4) void k1_main(const float* __restrict__ fv,
    const unsigned short* __restrict__ Wt, unsigned* __restrict__ part){
  constexpr int KC = DROI / SK;
  constexpr int NT = KC / 64;
  static_assert(NT >= 3, "pipeline needs >=3 tiles");
  __shared__ __align__(16) short lsA[2][8192];   // fv tile bf16 (16KB each)
  __shared__ __align__(16) short lsB[3][8192];   // Wt tile bf16, 3-deep rotation
  const int tid  = threadIdx.x;
  const int wave = tid >> 6, lane = tid & 63;

  // XCD-aware swizzle (nwg divisible by 8)
  const int nwg  = SK * BIMG;
  const int cpx  = nwg >> 3;
  const int orig = blockIdx.x;
  const int wg   = (orig & 7) * cpx + (orig >> 3);
  const int s = wg >> 4;
  const int b = wg & 15;
  const int kbase = s * KC;

  f32x4 acc[2][8];
  {
    f32x4 z = {0.f, 0.f, 0.f, 0.f};
#pragma unroll
    for (int m = 0; m < 2; ++m)
#pragma unroll
      for (int c = 0; c < 8; ++c) acc[m][c] = z;
  }

  const int r0   = tid >> 2;
  const int colf = (tid & 3) * 4;
  const int sw   = (r0 & 7) << 4;
  const float* fvt = fv + (long)(b * NDET + r0) * DROI + kbase + colf;
  const int hh  = lane >> 3;
  const int seg = (lane & 7) ^ hh;

  const int outw = wave >> 2;         // 0 = Gram, 1 = XW1
  const int mq   = wave & 3;          // M-quarter (32 rows)
  const int lq   = lane & 15;

  float4 stg[4];

  auto issueF = [&](int t){
    const float* fp = fvt + t * 64;
#pragma unroll
    for (int i = 0; i < 4; ++i) stg[i] = *(const float4*)(fp + i * 16);
  };
  auto issueG = [&](int t, int bufi){
#pragma unroll
    for (int j = 0; j < 2; ++j){
      int call = wave * 2 + j;
      int h = call * 8 + hh;
      const char* g = (const char*)Wt + (long)h * (DROI * 2)
                    + (long)(kbase + t * 64) * 2 + seg * 16;
      gl_lds16(g, (char*)lsB[bufi] + call * 1024);
    }
  };
  auto writeA = [&](int abuf){
    char* basep = (char*)lsA[abuf];
#pragma unroll
    for (int i = 0; i < 4; ++i){
      uint2 w; w.x = pk2(stg[i].x, stg[i].y); w.y = pk2(stg[i].z, stg[i].w);
      int bo = (colf + i * 16) * 2;
      *(uint2*)(basep + r0 * 128 + (bo ^ sw)) = w;
    }
  };

  // ---- prologue: A(0), B(0), B(1) ----
  issueF(0);
  __builtin_amdgcn_sched_barrier(0);
  issueG(0, 0);
  issueG(1, 1);
  __builtin_amdgcn_sched_barrier(0);
  writeA(0);                                        // auto-wait drains F0
  asm volatile("s_waitcnt vmcnt(2)" ::: "memory");  // drains G0; leaves G1
  asm volatile("s_waitcnt lgkmcnt(0)" ::: "memory");
  __builtin_amdgcn_sched_barrier(0);
  __builtin_amdgcn_s_barrier();
  __builtin_amdgcn_sched_barrier(0);

#pragma unroll
  for (int t = 0; t < NT; ++t){
    if (t + 1 < NT) issueF(t + 1);
    __builtin_amdgcn_sched_barrier(0);
    if (t + 2 < NT) issueG(t + 2, (t + 2) % 3);
    __builtin_amdgcn_sched_barrier(0);
    {
      const short* A  = lsA[t & 1];
      const short* Bs = outw ? lsB[t % 3] : lsA[t & 1];
#pragma unroll
      for (int kk = 0; kk < 2; ++kk){
        const int bo = kk * 64 + (lane >> 4) * 16;
        bf16x8 a0 = ldfrag128(A, mq * 32 + lq, bo);
        bf16x8 a1 = ldfrag128(A, mq * 32 + 16 + lq, bo);
#pragma unroll
        for (int cb = 0; cb < 8; ++cb){
          bf16x8 bb = ldfrag128(Bs, cb * 16 + lq, bo);
          acc[0][cb] = mfma16(a0, bb, acc[0][cb]);
          acc[1][cb] = mfma16(a1, bb, acc[1][cb]);
        }
      }
    }
    __builtin_amdgcn_sched_barrier(0);
    if (t + 1 < NT){
      writeA((t + 1) & 1);   // auto-wait drains F(t+1); FIFO also drains G(t+1)
      asm volatile("s_waitcnt lgkmcnt(0)" ::: "memory");
      __builtin_amdgcn_sched_barrier(0);
      __builtin_amdgcn_s_barrier();
      __builtin_amdgcn_sched_barrier(0);
    }
  }

  // ---- bf16 packed, fully-coalesced partial store ----
  const int slot = mq * 64 + lane;
  uint4* dst4 = (uint4*)(part + (((long)s * 32 + b * 2 + outw) * 8192));
#pragma unroll
  for (int g = 0; g < 8; ++g){
    const int m = g >> 2, cb0 = (g & 3) * 2;
    uint4 w;
    w.x = pk2(acc[m][cb0][0],     acc[m][cb0][1]);
    w.y = pk2(acc[m][cb0][2],     acc[m][cb0][3]);
    w.z = pk2(acc[m][cb0 + 1][0], acc[m][cb0 + 1][1]);
    w.w = pk2(acc[m][cb0 + 1][2], acc[m][cb0 + 1][3]);
    dst4[g * 256 + slot] = w;
  }
}

// ---------------- KR: split-K reduce, LDS transpose, coalesced both sides --
template<int SK>
__global__ __launch_bounds__(256) void k_reduce(const unsigned* __restrict__ part,
                                                float* __restrict__ fin){
  __shared__ float tile[16][33];
  const int tid = threadIdx.x;
  const int B   = blockIdx.x;            // 0..1023
  const int bo2 = B >> 5;                // b*2 + outw
  const int q   = (B & 31) * 256 + tid;  // within-part uint index
  float lo = 0.f, hi = 0.f;
  const unsigned* p = part + (long)bo2 * 8192 + q;
#pragma unroll
  for (int s = 0; s < SK; ++s){
    unsigned v = p[(long)s * 262144];
    lo += __uint_as_float(v << 16);
    hi += __uint_as_float(v & 0xffff0000u);
  }
  const int g    = q >> 10;
  const int slot = (q & 1023) >> 2;
  const int w    = q & 3;
  const int m  = g >> 2;
  const int cb1 = w >> 1;
  const int ip = w & 1;
  const int mq = slot >> 6, lane = slot & 63;
  const int r   = ((lane >> 4) << 2) + (ip << 1);
  const int col = (cb1 << 4) + (lane & 15);
  tile[r][col]     = lo;
  tile[r + 1][col] = hi;
  __syncthreads();
  const int Rbase = mq * 32 + m * 16;
  const int Cbase = (g & 3) * 32;
  float* f = fin + (long)bo2 * 16384;
  if ((bo2 & 1) == 0){
#pragma unroll
    for (int k = 0; k < 2; ++k){
      int idx = k * 256 + tid;
      int rr = idx >> 5, cc = idx & 31;
      f[(Rbase + rr) * 128 + Cbase + cc] = tile[rr][cc];
    }
  } else {
#pragma unroll
    for (int k = 0; k < 2; ++k){
      int idx = k * 256 + tid;
      int cc = idx >> 4, rr = idx & 15;
      f[(Cbase + cc) * 128 + Rbase + rr] = tile[rr][cc];
    }
  }
}

// ---------------- K2: fused adjacency + 3 GEMMs + pool + logits, 512 thr ---
__global__ __launch_bounds__(512, 1) void k2f(const float* __restrict__ fin,
    const float* __restrict__ ctr, const float* __restrict__ W1,
    const float* __restrict__ b1, const float* __restrict__ W2,
    const float* __restrict__ b2, const float* __restrict__ Wc,
    const float* __restrict__ bc, float* __restrict__ out){
  __shared__ __align__(16) short Ah[16384];   // normalized adjacency (persistent)
  __shared__ __align__(16) short Bu[16384];   // Yt -> H1 -> Tt
  __shared__ __align__(16) short Cu[16384];   // W2t -> pool scratch
  __shared__ float sm2[256];
  __shared__ float sctr[256];
  const int b   = blockIdx.x;
  const int tid = threadIdx.x;
  const float* G  = fin + (long)b * 32768;
  const float* Yt = G + 16384;                // stored TRANSPOSED: Yt[c][k]

  if (tid < 256) sctr[tid] = ctr[b * 256 + tid];
  if (tid < 128){
    float g = G[tid * 129];
    sm2[tid] = 1.0f / fmaxf(sqrtf(g), 1e-12f);
  }
  __syncthreads();

  // adjacency: thread (i, j-quarter of 32)
  const int   i   = tid >> 2;
  const int   jq  = (tid & 3) * 32;
  const float invni = sm2[i];
  const float cxi = sctr[2 * i], cyi = sctr[2 * i + 1];
  unsigned m0 = 0;
  int degloc = 0;
  for (int j4 = 0; j4 < 32; j4 += 4){
    float4 g4 = *(const float4*)(G + i * 128 + jq + j4);
    float gg[4] = {g4.x, g4.y, g4.z, g4.w};
#pragma unroll
    for (int u = 0; u < 4; ++u){
      int j = jq + j4 + u;
      float cs = gg[u] * invni * sm2[j];
      float dx = cxi - sctr[2 * j];
      float dy = cyi - sctr[2 * j + 1];
      float d2 = dx * dx + dy * dy;
      if (d2 < 2500.0f || cs > 0.8f){
        m0 |= (1u << (j4 + u));
        ++degloc;
      }
    }
  }
  if (i >= jq && i < jq + 32) ++degloc;       // self loop (exactly one quarter holds i)
  degloc += __shfl_xor(degloc, 1);
  degloc += __shfl_xor(degloc, 2);
  if ((tid & 3) == 0) sm2[128 + i] = rsqrtf((float)degloc);
  __syncthreads();

  {
    const float dinvi = sm2[128 + i];
    char* AhB = (char*)Ah;
#pragma unroll
    for (int jp = 0; jp < 32; jp += 2){
      int j0 = jq + jp, j1 = j0 + 1;
      float a0 = ((m0 >> jp)       & 1u) ? 1.f : 0.f;
      float a1 = ((m0 >> (jp + 1)) & 1u) ? 1.f : 0.f;
      if (i == j0) a0 += 1.f;
      if (i == j1) a1 += 1.f;
      float v0 = dinvi * a0 * sm2[128 + j0];
      float v1 = dinvi * a1 * sm2[128 + j1];
      int bo = j0 * 2;
      *(unsigned*)(AhB + i * 256 + (bo ^ ((i & 7) << 4))) = pk2(v0, v1);
    }
  }

  // stage W2t[c][k] into Cu (4 threads per col, 32 k each)
  {
    const int c  = tid & 127;
    const int kq = (tid >> 7) * 32;
    char* WB = (char*)Cu;
#pragma unroll
    for (int k8 = kq; k8 < kq + 32; k8 += 8){
      float f[8];
#pragma unroll
      for (int u = 0; u < 8; ++u) f[u] = W2[(k8 + u) * 128 + c];
      uint4 w;
      w.x = pk2(f[0], f[1]); w.y = pk2(f[2], f[3]);
      w.z = pk2(f[4], f[5]); w.w = pk2(f[6], f[7]);
      int bo = k8 * 2;
      *(uint4*)(WB + c * 256 + (bo ^ ((c & 7) << 4))) = w;
    }
  }
  // stage Yt tile from transposed fin + ctr tail (4 threads per row, 32 k)
  {
    const int cr = tid >> 2;
    const int kq = (tid & 3) * 32;
    const float w1a = W1[(long)12544 * NHID + cr];
    const float w1b = W1[(long)12545 * NHID + cr];
    const float* Yr = Yt + cr * 128 + kq;
    char* YtB = (char*)Bu;
#pragma unroll
    for (int k8 = 0; k8 < 32; k8 += 8){
      float4 va = *(const float4*)(Yr + k8);
      float4 vb = *(const float4*)(Yr + k8 + 4);
      float f[8] = {va.x, va.y, va.z, va.w, vb.x, vb.y, vb.z, vb.w};
#pragma unroll
      for (int u = 0; u < 8; ++u){
        int k = kq + k8 + u;
        f[u] += sctr[2 * k] * w1a + sctr[2 * k + 1] * w1b;
      }
      uint4 w;
      w.x = pk2(f[0], f[1]); w.y = pk2(f[2], f[3]);
      w.z = pk2(f[4], f[5]); w.w = pk2(f[6], f[7]);
      int bo = (kq + k8) * 2;
      *(uint4*)(YtB + cr * 256 + (bo ^ ((cr & 7) << 4))) = w;
    }
  }
  __syncthreads();

  const int wave = tid >> 6, lane = tid & 63;
  const int lq = lane & 15;
  f32x4 acc[8];
  f32x4 z4 = {0.f, 0.f, 0.f, 0.f};

  // GEMM1: H1 = relu(Ah @ Yt + b1) — wave owns 16 rows
#pragma unroll
  for (int cc = 0; cc < 8; ++cc) acc[cc] = z4;
#pragma unroll
  for (int ks = 0; ks < 4; ++ks){
    const int bo = ks * 64 + (lane >> 4) * 16;
    bf16x8 a0 = ldfrag256(Ah, wave * 16 + lq, bo);
#pragma unroll
    for (int cb = 0; cb < 8; ++cb){
      bf16x8 bb = ldfrag256(Bu, cb * 16 + lq, bo);
      acc[cb] = mfma16(a0, bb, acc[cb]);
    }
  }
  __syncthreads();
  {
    char* BuB = (char*)Bu;
    const int R0 = wave * 16 + (lane >> 4) * 4;
#pragma unroll
    for (int cb = 0; cb < 8; ++cb){
      const int C = cb * 16 + lq;
      const float bb1 = b1[C];
#pragma unroll
      for (int u = 0; u < 4; ++u){
        float v = fmaxf(acc[cb][u] + bb1, 0.f);
        int row = R0 + u;
        *(unsigned short*)(BuB + row * 256 + ((C * 2) ^ ((row & 7) << 4))) = bf1(v);
      }
    }
  }
  __syncthreads();

  // GEMM2: T = H1 @ W2t
#pragma unroll
  for (int cc = 0; cc < 8; ++cc) acc[cc] = z4;
#pragma unroll
  for (int ks = 0; ks < 4; ++ks){
    const int bo = ks * 64 + (lane >> 4) * 16;
    bf16x8 a0 = ldfrag256(Bu, wave * 16 + lq, bo);
#pragma unroll
    for (int cb = 0; cb < 8; ++cb){
      bf16x8 bb = ldfrag256(Cu, cb * 16 + lq, bo);
      acc[cb] = mfma16(a0, bb, acc[cb]);
    }
  }
  __syncthreads();
  {
    char* BuB = (char*)Bu;
    const int R0 = wave * 16 + (lane >> 4) * 4;
#pragma unroll
    for (int cb = 0; cb < 8; ++cb){
      const int C = cb * 16 + lq;
#pragma unroll
      for (int u = 0; u < 4; u += 2){
        int k = R0 + u;   // even
        unsigned w = pk2(acc[cb][u], acc[cb][u + 1]);
        *(unsigned*)(BuB + C * 256 + ((k * 2) ^ ((C & 7) << 4))) = w;
      }
    }
  }
  __syncthreads();

  // GEMM3: C2 = Ah @ Tt; relu(+b2); mean pool; logits
#pragma unroll
  for (int cc = 0; cc < 8; ++cc) acc[cc] = z4;
#pragma unroll
  for (int ks = 0; ks < 4; ++ks){
    const int bo = ks * 64 + (lane >> 4) * 16;
    bf16x8 a0 = ldfrag256(Ah, wave * 16 + lq, bo);
#pragma unroll
    for (int cb = 0; cb < 8; ++cb){
      bf16x8 bb = ldfrag256(Bu, cb * 16 + lq, bo);
      acc[cb] = mfma16(a0, bb, acc[cb]);
    }
  }
  float colp[8];
#pragma unroll
  for (int cb = 0; cb < 8; ++cb){
    const float bb2 = b2[cb * 16 + lq];
    float sum = 0.f;
#pragma unroll
    for (int u = 0; u < 4; ++u)
      sum += fmaxf(acc[cb][u] + bb2, 0.f);
    colp[cb] = sum;
  }
#pragma unroll
  for (int cb = 0; cb < 8; ++cb){
    float v = colp[cb];
    v += __shfl_xor(v, 16);
    v += __shfl_xor(v, 32);
    colp[cb] = v;
  }
  float* hgp = (float*)Cu;            // [8][128] partial col sums (Cu dead after GEMM2)
  if ((lane >> 4) == 0){
#pragma unroll
    for (int cb = 0; cb < 8; ++cb)
      hgp[wave * 128 + cb * 16 + lane] = colp[cb];
  }
  __syncthreads();
  float* hg = hgp + 1024;
  if (tid < 128){
    float s = 0.f;
#pragma unroll
    for (int w = 0; w < 8; ++w) s += hgp[w * 128 + tid];
    hg[tid] = s * (1.0f / 128.0f);
  }
  __syncthreads();
  if (tid < 22){
    float a2 = bc[tid];
    for (int h = 0; h < 128; ++h) a2 += hg[h] * Wc[h * 22 + tid];
    out[b * 22 + tid] = a2;
  }
}

// ---------------- launch ----------------
extern "C" void kernel_launch(void* const* d_in, const int* in_sizes, int n_in,
                              void* d_out, int out_size, void* d_ws, size_t ws_size,
                              hipStream_t stream){
  (void)in_sizes; (void)n_in; (void)out_size;
  const float* fv  = (const float*)d_in[0];
  const float* ctr = (const float*)d_in[1];
  const float* W1  = (const float*)d_in[2];
  const float* b1  = (const float*)d_in[3];
  const float* W2  = (const float*)d_in[4];
  const float* b2  = (const float*)d_in[5];
  const float* Wc  = (const float*)d_in[6];
  const float* bc  = (const float*)d_in[7];
  char* ws = (char*)d_ws;
  float* out = (float*)d_out;

  const unsigned long SZ_WT  = (unsigned long)NHID * DROI * 2;   // 3,211,264
  const unsigned long SZ_FIN = (unsigned long)BIMG * 2 * 16384 * 4;

  const unsigned long need28 = SZ_WT + 28UL * 1048576UL + SZ_FIN;
  const bool big = (ws_size >= need28);
  const int SK = big ? 28 : 14;

  unsigned short* Wt   = (unsigned short*)(ws);
  unsigned*       part = (unsigned*)(ws + SZ_WT);
  float*          fin  = (float*)(ws + SZ_WT + (unsigned long)SK * 1048576UL);

  k0_wt<<<dim3(DROI / 64), dim3(256), 0, stream>>>(W1, Wt);
  if (big){
    k1_main<28><<<dim3(28 * BIMG), dim3(512), 0, stream>>>(fv, Wt, part);
    k_reduce<28><<<dim3(1024), dim3(256), 0, stream>>>(part, fin);
  } else {
    k1_main<14><<<dim3(14 * BIMG), dim3(512), 0, stream>>>(fv, Wt, part);
    k_reduce<14><<<dim3(1024), dim3(256), 0, stream>>>(part, fin);
  }
  k2f<<<dim3(BIMG), dim3(512), 0, stream>>>(fin, ctr, W1, b1, W2, b2, Wc, bc, out);
}